// Round 1
// baseline (176.196 us; speedup 1.0000x reference)
//
#include <hip/hip_runtime.h>
#include <cstdint>

#define NB    128
#define NCIN  1024
#define NCOUT 1024
#define NHID  256
#define NHW   1024   // 32*32 spatial elements per (b, c)

// ---------------------------------------------------------------------------
// Kernel 1: global average pool over H*W. One wave (64 lanes) per (b, c_in)
// row of 1024 contiguous floats. float4 loads (16B/lane), f64 accumulation
// (sign of downstream g must be accurate), wave shuffle reduce.
// Memory-bound: 512 MiB read -> the roofline of this whole problem.
// ---------------------------------------------------------------------------
__global__ __launch_bounds__(256) void gap_kernel(const float* __restrict__ in,
                                                  float* __restrict__ x) {
    const int row  = blockIdx.x * 4 + (threadIdx.x >> 6);   // 4 waves/block
    const int lane = threadIdx.x & 63;
    const float4* p = reinterpret_cast<const float4*>(in) + (size_t)row * (NHW / 4);
    double s = 0.0;
#pragma unroll
    for (int k = 0; k < 4; ++k) {                 // 4 float4 = 16 floats/lane
        float4 v = p[lane + 64 * k];
        s += (double)v.x + (double)v.y + (double)v.z + (double)v.w;
    }
#pragma unroll
    for (int off = 32; off > 0; off >>= 1)
        s += __shfl_down(s, off, 64);
    if (lane == 0) x[row] = (float)(s * (1.0 / 1024.0));
}

// ---------------------------------------------------------------------------
// Kernel 2: y = relu(x @ fc1_w^T + fc1_b). One block per batch row; x row
// staged in LDS (broadcast reads, conflict-free); thread h owns output h.
// fc1_w is 1 MiB -> L2-resident after first touch. f64 accumulation.
// ---------------------------------------------------------------------------
__global__ __launch_bounds__(256) void fc1_kernel(const float* __restrict__ x,
                                                  const float* __restrict__ w1,
                                                  const float* __restrict__ b1,
                                                  float* __restrict__ y) {
    __shared__ float xs[NCIN];
    const int b = blockIdx.x;
    const int h = threadIdx.x;
    for (int c = threadIdx.x; c < NCIN; c += 256) xs[c] = x[b * NCIN + c];
    __syncthreads();

    const float4* w = reinterpret_cast<const float4*>(w1) + (size_t)h * (NCIN / 4);
    double a0 = 0.0, a1 = 0.0, a2 = 0.0, a3 = 0.0;
#pragma unroll 8
    for (int c4 = 0; c4 < NCIN / 4; ++c4) {
        float4 wv = w[c4];
        a0 += (double)wv.x * (double)xs[4 * c4 + 0];
        a1 += (double)wv.y * (double)xs[4 * c4 + 1];
        a2 += (double)wv.z * (double)xs[4 * c4 + 2];
        a3 += (double)wv.w * (double)xs[4 * c4 + 3];
    }
    double v = ((a0 + a1) + (a2 + a3)) + (double)b1[h];
    y[b * NHID + h] = (float)(v > 0.0 ? v : 0.0);
}

// ---------------------------------------------------------------------------
// Kernel 3: y2 = y @ fc2_w^T + fc2_b; g = noise + y2;
// v1 = clip(1.2*sigmoid(g)-0.1, 0, 1); v2 = (g>0); out = swapped? v2 : v1.
// One block per batch row; y row (256 f32) in LDS; swap membership via
// cooperative scan of the 512 swap indices into a shared flag.
// ---------------------------------------------------------------------------
__global__ __launch_bounds__(256) void fc2_kernel(const float* __restrict__ y,
                                                  const float* __restrict__ w2,
                                                  const float* __restrict__ b2,
                                                  const float* __restrict__ noise,
                                                  const int* __restrict__ swap_idx,
                                                  int n_swap,
                                                  float* __restrict__ out) {
    __shared__ float ys[NHID];
    __shared__ int flag;
    const int b = blockIdx.x;
    if (threadIdx.x == 0) flag = 0;
    if (threadIdx.x < NHID) ys[threadIdx.x] = y[b * NHID + threadIdx.x];
    __syncthreads();
    for (int i = threadIdx.x; i < n_swap; i += 256)
        if (swap_idx[i] == b) flag = 1;   // benign race: same value
    __syncthreads();
    const bool sw = (flag != 0);

#pragma unroll
    for (int k = 0; k < NCOUT / 256; ++k) {
        const int j = threadIdx.x + 256 * k;
        const float4* w = reinterpret_cast<const float4*>(w2) + (size_t)j * (NHID / 4);
        double a0 = 0.0, a1 = 0.0, a2 = 0.0, a3 = 0.0;
#pragma unroll 8
        for (int h4 = 0; h4 < NHID / 4; ++h4) {
            float4 wv = w[h4];
            a0 += (double)wv.x * (double)ys[4 * h4 + 0];
            a1 += (double)wv.y * (double)ys[4 * h4 + 1];
            a2 += (double)wv.z * (double)ys[4 * h4 + 2];
            a3 += (double)wv.w * (double)ys[4 * h4 + 3];
        }
        double g = ((a0 + a1) + (a2 + a3)) + (double)b2[j] + (double)noise[b * NCOUT + j];
        float gf  = (float)g;
        float sig = 1.0f / (1.0f + __expf(-gf));
        float v1  = 1.2f * sig - 0.1f;
        v1 = fminf(fmaxf(v1, 0.0f), 1.0f);
        float v2 = (g > 0.0) ? 1.0f : 0.0f;
        out[(size_t)b * NCOUT + j] = sw ? v2 : v1;
    }
}

extern "C" void kernel_launch(void* const* d_in, const int* in_sizes, int n_in,
                              void* d_out, int out_size, void* d_ws, size_t ws_size,
                              hipStream_t stream) {
    const float* input = (const float*)d_in[0];   // [128,1024,32,32]
    const float* fc1_w = (const float*)d_in[1];   // [256,1024]
    const float* fc1_b = (const float*)d_in[2];   // [256]
    const float* fc2_w = (const float*)d_in[3];   // [1024,256]
    const float* fc2_b = (const float*)d_in[4];   // [1024]
    const float* noise = (const float*)d_in[5];   // [128,1024]
    const int*   swap  = (const int*)d_in[6];     // [512]
    const int n_swap = in_sizes[6];

    float* x = (float*)d_ws;          // [128,1024]  = 512 KiB
    float* y = x + NB * NCIN;         // [128,256]   = 128 KiB

    gap_kernel<<<(NB * NCIN) / 4, 256, 0, stream>>>(input, x);
    fc1_kernel<<<NB, 256, 0, stream>>>(x, fc1_w, fc1_b, y);
    fc2_kernel<<<NB, 256, 0, stream>>>(y, fc2_w, fc2_b, noise, swap, n_swap,
                                       (float*)d_out);
}

// Round 3
// 119.014 us; speedup vs baseline: 1.4805x; 1.4805x over previous
//
#include <hip/hip_runtime.h>
#include <cstdint>

#define NB    128
#define NCIN  1024
#define NCOUT 1024
#define NHID  256
#define NHW   1024   // 32*32 spatial elements per (b, c)

typedef float f32x4 __attribute__((ext_vector_type(4)));  // clang vector: OK for nontemporal builtins

// ---------------------------------------------------------------------------
// Kernel 1: global average pool. One wave per 4 consecutive (b,c) rows of
// 1024 contiguous floats each. Nontemporal 16B loads (streaming, no reuse),
// pairwise f32 within each vec4, f64 accumulate + f64 shuffle reduce
// (downstream g-sign accuracy). Memory-bound: 512 MiB read.
// ---------------------------------------------------------------------------
__global__ __launch_bounds__(256) void gap_kernel(const float* __restrict__ in,
                                                  float* __restrict__ x) {
    const int wave = (blockIdx.x * 256 + threadIdx.x) >> 6;   // global wave id
    const int lane = threadIdx.x & 63;
    const int row0 = wave * 4;
    const f32x4* base = reinterpret_cast<const f32x4*>(in);
#pragma unroll
    for (int r = 0; r < 4; ++r) {
        const f32x4* p = base + (size_t)(row0 + r) * (NHW / 4);
        f32x4 v0 = __builtin_nontemporal_load(p + lane);
        f32x4 v1 = __builtin_nontemporal_load(p + lane + 64);
        f32x4 v2 = __builtin_nontemporal_load(p + lane + 128);
        f32x4 v3 = __builtin_nontemporal_load(p + lane + 192);
        float t0 = (v0.x + v0.y) + (v0.z + v0.w);
        float t1 = (v1.x + v1.y) + (v1.z + v1.w);
        float t2 = (v2.x + v2.y) + (v2.z + v2.w);
        float t3 = (v3.x + v3.y) + (v3.z + v3.w);
        double s = ((double)t0 + (double)t1) + ((double)t2 + (double)t3);
#pragma unroll
        for (int off = 32; off > 0; off >>= 1)
            s += __shfl_down(s, off, 64);
        if (lane == 0) x[row0 + r] = (float)(s * (1.0 / 1024.0));
    }
}

// ---------------------------------------------------------------------------
// Kernel 2: y = relu(x @ fc1_w^T + fc1_b). 512 blocks: (b, h-quadrant).
// Threads split 4-way over c (4 × 256-c partial dots, independent f64
// chains), LDS combine. x row staged in LDS.
// ---------------------------------------------------------------------------
__global__ __launch_bounds__(256) void fc1_kernel(const float* __restrict__ x,
                                                  const float* __restrict__ w1,
                                                  const float* __restrict__ b1,
                                                  float* __restrict__ y) {
    __shared__ float  xs[NCIN];
    __shared__ double part[64][4];
    const int b  = blockIdx.x >> 2;
    const int hq = blockIdx.x & 3;
    const int t  = threadIdx.x;

    reinterpret_cast<float4*>(xs)[t] =
        reinterpret_cast<const float4*>(x + (size_t)b * NCIN)[t];
    __syncthreads();

    const int hl = t & 63;          // h within quadrant
    const int cs = t >> 6;          // c-split 0..3
    const int h  = hq * 64 + hl;
    const float4* w  = reinterpret_cast<const float4*>(w1 + (size_t)h * NCIN + cs * 256);
    const float*  xp = xs + cs * 256;
    double a0 = 0.0, a1 = 0.0, a2 = 0.0, a3 = 0.0;
#pragma unroll 8
    for (int i = 0; i < 64; ++i) {
        float4 wv = w[i];
        a0 += (double)wv.x * (double)xp[4 * i + 0];
        a1 += (double)wv.y * (double)xp[4 * i + 1];
        a2 += (double)wv.z * (double)xp[4 * i + 2];
        a3 += (double)wv.w * (double)xp[4 * i + 3];
    }
    part[hl][cs] = (a0 + a1) + (a2 + a3);
    __syncthreads();

    if (t < 64) {
        double v = ((part[t][0] + part[t][1]) + (part[t][2] + part[t][3]))
                 + (double)b1[hq * 64 + t];
        y[(size_t)b * NHID + hq * 64 + t] = (float)(v > 0.0 ? v : 0.0);
    }
}

// ---------------------------------------------------------------------------
// Kernel 3: g = y @ fc2_w^T + fc2_b + noise; v1 = clip(1.2*sig(g)-0.1,0,1);
// v2 = (g>0); out = row-swapped ? v2 : v1. 512 blocks: (b, j-quadrant),
// one j per thread (256-elem f64 dot). y row in LDS; swap flag via scan.
// ---------------------------------------------------------------------------
__global__ __launch_bounds__(256) void fc2_kernel(const float* __restrict__ y,
                                                  const float* __restrict__ w2,
                                                  const float* __restrict__ b2,
                                                  const float* __restrict__ noise,
                                                  const int* __restrict__ swap_idx,
                                                  int n_swap,
                                                  float* __restrict__ out) {
    __shared__ float ys[NHID];
    __shared__ int flag;
    const int b  = blockIdx.x >> 2;
    const int jq = blockIdx.x & 3;
    const int t  = threadIdx.x;

    if (t == 0) flag = 0;
    ys[t] = y[(size_t)b * NHID + t];
    __syncthreads();
    for (int i = t; i < n_swap; i += 256)
        if (swap_idx[i] == b) flag = 1;   // benign race: same value
    __syncthreads();
    const bool sw = (flag != 0);

    const int j = jq * 256 + t;
    const float4* w = reinterpret_cast<const float4*>(w2 + (size_t)j * NHID);
    double a0 = 0.0, a1 = 0.0, a2 = 0.0, a3 = 0.0;
#pragma unroll 8
    for (int i = 0; i < NHID / 4; ++i) {
        float4 wv = w[i];
        a0 += (double)wv.x * (double)ys[4 * i + 0];
        a1 += (double)wv.y * (double)ys[4 * i + 1];
        a2 += (double)wv.z * (double)ys[4 * i + 2];
        a3 += (double)wv.w * (double)ys[4 * i + 3];
    }
    double g = ((a0 + a1) + (a2 + a3)) + (double)b2[j]
             + (double)noise[(size_t)b * NCOUT + j];
    float gf  = (float)g;
    float sig = 1.0f / (1.0f + __expf(-gf));
    float v1  = fminf(fmaxf(1.2f * sig - 0.1f, 0.0f), 1.0f);
    float v2  = (g > 0.0) ? 1.0f : 0.0f;
    out[(size_t)b * NCOUT + j] = sw ? v2 : v1;
}

extern "C" void kernel_launch(void* const* d_in, const int* in_sizes, int n_in,
                              void* d_out, int out_size, void* d_ws, size_t ws_size,
                              hipStream_t stream) {
    const float* input = (const float*)d_in[0];   // [128,1024,32,32]
    const float* fc1_w = (const float*)d_in[1];   // [256,1024]
    const float* fc1_b = (const float*)d_in[2];   // [256]
    const float* fc2_w = (const float*)d_in[3];   // [1024,256]
    const float* fc2_b = (const float*)d_in[4];   // [1024]
    const float* noise = (const float*)d_in[5];   // [128,1024]
    const int*   swap  = (const int*)d_in[6];     // [512]
    const int n_swap = in_sizes[6];

    float* x = (float*)d_ws;          // [128,1024]  = 512 KiB
    float* y = x + NB * NCIN;         // [128,256]   = 128 KiB

    gap_kernel<<<(NB * NCIN) / 16, 256, 0, stream>>>(input, x);   // 2048 blocks
    fc1_kernel<<<NB * 4, 256, 0, stream>>>(x, fc1_w, fc1_b, y);
    fc2_kernel<<<NB * 4, 256, 0, stream>>>(y, fc2_w, fc2_b, noise, swap, n_swap,
                                           (float*)d_out);
}

// Round 4
// 118.961 us; speedup vs baseline: 1.4811x; 1.0004x over previous
//
#include <hip/hip_runtime.h>
#include <cstdint>

#define NB    128
#define NCIN  1024
#define NCOUT 1024
#define NHID  256
#define NHW   1024   // 32*32 spatial elements per (b, c)

#define WARM_BLOCKS 16
#define GAP_BLOCKS  ((NB * NCIN) / 16)   // 8192: 4 waves/block, 4 rows/wave

typedef float f32x4 __attribute__((ext_vector_type(4)));  // clang vector for nontemporal builtins

// ---------------------------------------------------------------------------
// Kernel 1: global average pool (memory-bound roofline: 512 MiB read).
// Blocks [0,16): cache-warm w1/w2/noise (2.5 MiB) concurrently with GAP so
// fc1/fc2 hit L2/L3 instead of cold HBM. Blocks [16, 16+8192): one wave per
// 4 consecutive (b,c) rows; nontemporal 16B loads (streaming — don't evict
// the warmed weights), pairwise f32 then f64 accumulate + f64 shuffle reduce
// (downstream g-sign accuracy).
// ---------------------------------------------------------------------------
__global__ __launch_bounds__(256) void gap_kernel(const float* __restrict__ in,
                                                  float* __restrict__ x,
                                                  const float* __restrict__ w1,
                                                  const float* __restrict__ w2,
                                                  const float* __restrict__ noise) {
    if (blockIdx.x < WARM_BLOCKS) {
        // Strided streaming of w1 (64K float4), w2 (64K float4), noise (32K float4).
        const int start = blockIdx.x * 256 + threadIdx.x;
        float acc = 0.f;
        const float4* p1 = reinterpret_cast<const float4*>(w1);
        const float4* p2 = reinterpret_cast<const float4*>(w2);
        const float4* pn = reinterpret_cast<const float4*>(noise);
        for (int i = start; i < (NHID * NCIN) / 4; i += WARM_BLOCKS * 256) {
            float4 v = p1[i]; acc += (v.x + v.y) + (v.z + v.w);
        }
        for (int i = start; i < (NCOUT * NHID) / 4; i += WARM_BLOCKS * 256) {
            float4 v = p2[i]; acc += (v.x + v.y) + (v.z + v.w);
        }
        for (int i = start; i < (NB * NCOUT) / 4; i += WARM_BLOCKS * 256) {
            float4 v = pn[i]; acc += (v.x + v.y) + (v.z + v.w);
        }
        asm volatile("" :: "v"(acc));   // keep loads alive (no DCE)
        return;
    }

    const int wave = ((blockIdx.x - WARM_BLOCKS) * 256 + threadIdx.x) >> 6;
    const int lane = threadIdx.x & 63;
    const int row0 = wave * 4;
    const f32x4* base = reinterpret_cast<const f32x4*>(in);
#pragma unroll
    for (int r = 0; r < 4; ++r) {
        const f32x4* p = base + (size_t)(row0 + r) * (NHW / 4);
        f32x4 v0 = __builtin_nontemporal_load(p + lane);
        f32x4 v1 = __builtin_nontemporal_load(p + lane + 64);
        f32x4 v2 = __builtin_nontemporal_load(p + lane + 128);
        f32x4 v3 = __builtin_nontemporal_load(p + lane + 192);
        float t0 = (v0.x + v0.y) + (v0.z + v0.w);
        float t1 = (v1.x + v1.y) + (v1.z + v1.w);
        float t2 = (v2.x + v2.y) + (v2.z + v2.w);
        float t3 = (v3.x + v3.y) + (v3.z + v3.w);
        double s = ((double)t0 + (double)t1) + ((double)t2 + (double)t3);
#pragma unroll
        for (int off = 32; off > 0; off >>= 1)
            s += __shfl_down(s, off, 64);
        if (lane == 0) x[row0 + r] = (float)(s * (1.0 / 1024.0));
    }
}

// ---------------------------------------------------------------------------
// Kernel 2: y = relu(x @ fc1_w^T + fc1_b). 1024 blocks: (b, 8 h-groups of 32).
// 256 threads = 32 h × 8 c-splits (chain length 32). x row staged as padded
// float4 LDS xs4[8][33] -> conflict-free ds_read_b128 broadcasts. 8-way
// partial combine via __shfl_xor (f64).
// ---------------------------------------------------------------------------
__global__ __launch_bounds__(256) void fc1_kernel(const float* __restrict__ x,
                                                  const float* __restrict__ w1,
                                                  const float* __restrict__ b1,
                                                  float* __restrict__ y) {
    __shared__ float4 xs4[8][33];   // padded: stride 33 breaks bank aliasing
    const int b  = blockIdx.x >> 3;
    const int ho = blockIdx.x & 7;
    const int t  = threadIdx.x;

    {
        float4 v = reinterpret_cast<const float4*>(x + (size_t)b * NCIN)[t];
        xs4[t >> 5][t & 31] = v;
    }
    __syncthreads();

    const int hl = t >> 3;          // 0..31: h within group
    const int cs = t & 7;           // 0..7: c-split
    const int h  = ho * 32 + hl;
    const float4* w = reinterpret_cast<const float4*>(w1 + (size_t)h * NCIN + cs * 128);
    double a0 = 0.0, a1 = 0.0, a2 = 0.0, a3 = 0.0;
#pragma unroll
    for (int i = 0; i < 32; ++i) {
        float4 wv = w[i];
        float4 xv = xs4[cs][i];
        a0 += (double)wv.x * (double)xv.x;
        a1 += (double)wv.y * (double)xv.y;
        a2 += (double)wv.z * (double)xv.z;
        a3 += (double)wv.w * (double)xv.w;
    }
    double s = (a0 + a1) + (a2 + a3);
    s += __shfl_xor(s, 1, 64);
    s += __shfl_xor(s, 2, 64);
    s += __shfl_xor(s, 4, 64);
    if (cs == 0) {
        double v = s + (double)b1[h];
        y[(size_t)b * NHID + h] = (float)(v > 0.0 ? v : 0.0);
    }
}

// ---------------------------------------------------------------------------
// Kernel 3: g = y @ fc2_w^T + fc2_b + noise; v1 = clip(1.2*sig(g)-0.1,0,1);
// v2 = (g>0); out = row-swapped ? v2 : v1. 1024 blocks: (b, 8 j-groups of
// 128). 256 threads = 128 j × 2 c-halves (chain length 32), pair combine via
// __shfl_xor(1). ys broadcast reads are 2-way bank aliased = free.
// ---------------------------------------------------------------------------
__global__ __launch_bounds__(256) void fc2_kernel(const float* __restrict__ y,
                                                  const float* __restrict__ w2,
                                                  const float* __restrict__ b2,
                                                  const float* __restrict__ noise,
                                                  const int* __restrict__ swap_idx,
                                                  int n_swap,
                                                  float* __restrict__ out) {
    __shared__ float ys[NHID];
    __shared__ int flag;
    const int b  = blockIdx.x >> 3;
    const int jo = blockIdx.x & 7;
    const int t  = threadIdx.x;

    if (t == 0) flag = 0;
    ys[t] = y[(size_t)b * NHID + t];
    __syncthreads();
    for (int i = t; i < n_swap; i += 256)
        if (swap_idx[i] == b) flag = 1;   // benign race: same value
    __syncthreads();
    const bool sw = (flag != 0);

    const int jl = t >> 1;          // 0..127
    const int ch = t & 1;           // 0..1
    const int j  = jo * 128 + jl;
    const float4* w  = reinterpret_cast<const float4*>(w2 + (size_t)j * NHID + ch * 128);
    const float*  yp = ys + ch * 128;
    double a0 = 0.0, a1 = 0.0, a2 = 0.0, a3 = 0.0;
#pragma unroll
    for (int i = 0; i < 32; ++i) {
        float4 wv = w[i];
        a0 += (double)wv.x * (double)yp[4 * i + 0];
        a1 += (double)wv.y * (double)yp[4 * i + 1];
        a2 += (double)wv.z * (double)yp[4 * i + 2];
        a3 += (double)wv.w * (double)yp[4 * i + 3];
    }
    double s = (a0 + a1) + (a2 + a3);
    s += __shfl_xor(s, 1, 64);
    if (ch == 0) {
        double g = s + (double)b2[j] + (double)noise[(size_t)b * NCOUT + j];
        float gf  = (float)g;
        float sig = 1.0f / (1.0f + __expf(-gf));
        float v1  = fminf(fmaxf(1.2f * sig - 0.1f, 0.0f), 1.0f);
        float v2  = (g > 0.0) ? 1.0f : 0.0f;
        out[(size_t)b * NCOUT + j] = sw ? v2 : v1;
    }
}

extern "C" void kernel_launch(void* const* d_in, const int* in_sizes, int n_in,
                              void* d_out, int out_size, void* d_ws, size_t ws_size,
                              hipStream_t stream) {
    const float* input = (const float*)d_in[0];   // [128,1024,32,32]
    const float* fc1_w = (const float*)d_in[1];   // [256,1024]
    const float* fc1_b = (const float*)d_in[2];   // [256]
    const float* fc2_w = (const float*)d_in[3];   // [1024,256]
    const float* fc2_b = (const float*)d_in[4];   // [1024]
    const float* noise = (const float*)d_in[5];   // [128,1024]
    const int*   swap  = (const int*)d_in[6];     // [512]
    const int n_swap = in_sizes[6];

    float* x = (float*)d_ws;          // [128,1024]  = 512 KiB
    float* y = x + NB * NCIN;         // [128,256]   = 128 KiB

    gap_kernel<<<WARM_BLOCKS + GAP_BLOCKS, 256, 0, stream>>>(input, x, fc1_w,
                                                             fc2_w, noise);
    fc1_kernel<<<NB * 8, 256, 0, stream>>>(x, fc1_w, fc1_b, y);
    fc2_kernel<<<NB * 8, 256, 0, stream>>>(y, fc2_w, fc2_b, noise, swap, n_swap,
                                           (float*)d_out);
}